// Round 9
// baseline (205.498 us; speedup 1.0000x reference)
//
#include <hip/hip_runtime.h>
#include <hip/hip_bf16.h>

typedef float v2f    __attribute__((ext_vector_type(2)));
typedef float v4f    __attribute__((ext_vector_type(4)));
typedef float f32x16 __attribute__((ext_vector_type(16)));
typedef __bf16 bf16x8 __attribute__((ext_vector_type(8)));

#define BATCH 4096
#define NF 26
#define NV 100000
#define ND_ 16      // embedding dim D (= MFMA K)
#define NA 16       // attention dim A
#define NDENSE 13
#define NPAIR 325   // NF*(NF-1)/2
#define ROWP 20     // padded LDS row stride in floats (80B)
#define WPB 4       // waves per block, 1 item per wave
#define BLOCK (WPB * 64)
#define NTILE 11    // ceil(325/32) MFMA tiles per item
#define REPS 32     // DIAGNOSTIC: amortize fixed overhead + surface counters

__global__ __launch_bounds__(BLOCK) void afm_kernel(
    const float* __restrict__ dense,     // [B, 13]
    const int*   __restrict__ sparse,    // [B, 26]
    const float* __restrict__ tables,    // [26, 100000, 16]
    const float* __restrict__ attW,      // [16, 16] row-major [d][k]
    const float* __restrict__ attB,      // [16]
    const float* __restrict__ attH,      // [16]
    const float* __restrict__ attP,      // [16]
    const float* __restrict__ wDense,    // [13]
    const float* __restrict__ wSparse,   // [416]
    const float* __restrict__ linB,      // [1]
    float* __restrict__ out)             // [B]
{
    __shared__ int sOFF[NPAIR];                       // (i*ROWP) | (j*ROWP)<<16
    __shared__ __align__(16) float sEmb[WPB][NF * ROWP];

    const int tid  = threadIdx.x;
    const int wave = tid >> 6;
    const int lane = tid & 63;
    const int col  = lane & 31;
    const int hi   = lane >> 5;
    const int b    = blockIdx.x * WPB + wave;

    // ---- pair offset table (one-time) ----
    for (int p = tid; p < NPAIR; p += BLOCK) {
        int i = 0, rem = p;
        while (rem >= NF - 1 - i) { rem -= NF - 1 - i; ++i; }
        const int j = i + 1 + rem;
        sOFF[p] = (i * ROWP) | ((j * ROWP) << 16);
    }

    // ---- A-fragment + post weights (one-time) ----
    bf16x8 afrag;
    #pragma unroll
    for (int t = 0; t < 8; ++t) {
        float a = 0.f;
        if (col < NA)       a = attW[(hi * 8 + t) * NA + col];
        else if (col == NA) a = attP[hi * 8 + t];
        afrag[t] = (__bf16)a;
    }
    float  hreg[8];
    f32x16 cinit = {0.f,0.f,0.f,0.f,0.f,0.f,0.f,0.f,0.f,0.f,0.f,0.f,0.f,0.f,0.f,0.f};
    #pragma unroll
    for (int r = 0; r < 8; ++r) {
        const int k = (r & 3) + 8 * (r >> 2) + 4 * hi;
        hreg[r]  = attH[k];
        cinit[r] = attB[k];
    }

    for (int rep = 0; rep < REPS; ++rep) {
        asm volatile("" ::: "memory");   // force genuine re-execution

        // ---- sparse indices + gather (reps >=2 are L2-warm) ----
        int idxreg = 0;
        if (lane < NF) idxreg = sparse[b * NF + lane];
        #pragma unroll
        for (int rnd = 0; rnd < 2; ++rnd) {
            const int c = lane + rnd * 64;
            if (c < (NF * ND_) / 4) {
                const int f  = c >> 2;
                const int d4 = (c & 3) << 2;
                const int row = __shfl(idxreg, f);
                const float4 v = *reinterpret_cast<const float4*>(
                    tables + ((size_t)f * NV + (size_t)row) * ND_ + d4);
                *reinterpret_cast<float4*>(&sEmb[wave][f * ROWP + d4]) = v;
            }
        }

        __syncthreads();

        const float* __restrict__ semb = sEmb[wave];

        // ---- linear term ----
        float lin = 0.f;
        #pragma unroll
        for (int rnd = 0; rnd < 7; ++rnd) {
            const int e = lane + rnd * 64;
            if (e < NF * ND_)
                lin += semb[(e >> 4) * ROWP + (e & 15)] * wSparse[e];
        }
        if (lane < NDENSE)
            lin += dense[b * NDENSE + lane] * wDense[lane];

        // ---- MFMA tile loop ----
        float num = 0.f, den = 0.f;
        #pragma unroll
        for (int t = 0; t < NTILE; ++t) {
            const int p     = t * 32 + col;
            const bool valid = (p < NPAIR) && (hi == 0);
            const int pc    = (p < NPAIR) ? p : (NPAIR - 1);
            const int offs  = sOFF[pc];
            const float* ri = semb + (offs & 0xffff) + hi * 8;
            const float* rj = semb + (offs >> 16)    + hi * 8;

            const v4f x0 = *reinterpret_cast<const v4f*>(ri);
            const v4f x1 = *reinterpret_cast<const v4f*>(ri + 4);
            const v4f y0 = *reinterpret_cast<const v4f*>(rj);
            const v4f y1 = *reinterpret_cast<const v4f*>(rj + 4);
            const v4f e0 = x0 * y0;
            const v4f e1 = x1 * y1;

            bf16x8 bfrag;
            bfrag[0] = (__bf16)e0[0]; bfrag[1] = (__bf16)e0[1];
            bfrag[2] = (__bf16)e0[2]; bfrag[3] = (__bf16)e0[3];
            bfrag[4] = (__bf16)e1[0]; bfrag[5] = (__bf16)e1[1];
            bfrag[6] = (__bf16)e1[2]; bfrag[7] = (__bf16)e1[3];

            const f32x16 acc =
                __builtin_amdgcn_mfma_f32_32x32x16_bf16(afrag, bfrag, cinit, 0, 0, 0);

            v2f sp2 = {0.f, 0.f};
            #pragma unroll
            for (int r = 0; r < 4; ++r) {
                v2f z;  z.x = acc[2 * r];  z.y = acc[2 * r + 1];
                v2f zr; zr.x = fmaxf(z.x, 0.f); zr.y = fmaxf(z.y, 0.f);
                v2f h;  h.x = hreg[2 * r]; h.y = hreg[2 * r + 1];
                sp2 = zr * h + sp2;
            }
            const float sp = sp2.x + sp2.y;
            const float sfull = sp + __shfl_xor(sp, 32);

            const float ev = valid ? __expf(sfull) : 0.f;
            num = fmaf(ev, acc[8], num);
            den += ev;
        }

        // ---- wave-reduce, finalize (write only on last rep) ----
        #pragma unroll
        for (int o = 32; o; o >>= 1) {
            num += __shfl_xor(num, o);
            den += __shfl_xor(den, o);
            lin += __shfl_xor(lin, o);
        }
        if (rep == REPS - 1 && lane == 0) {
            const float x = num / den + lin + linB[0];
            out[b] = 1.f / (1.f + __expf(-x));
        }
        __syncthreads();
    }
}

extern "C" void kernel_launch(void* const* d_in, const int* in_sizes, int n_in,
                              void* d_out, int out_size, void* d_ws, size_t ws_size,
                              hipStream_t stream) {
    const float* dense   = (const float*)d_in[0];
    const int*   sparse  = (const int*)d_in[1];
    const float* tables  = (const float*)d_in[2];
    const float* attW    = (const float*)d_in[3];
    const float* attB    = (const float*)d_in[4];
    const float* attH    = (const float*)d_in[5];
    const float* attP    = (const float*)d_in[6];
    const float* wDense  = (const float*)d_in[7];
    const float* wSparse = (const float*)d_in[8];
    const float* linB    = (const float*)d_in[9];
    float* out = (float*)d_out;

    const int grid = BATCH / WPB;  // 1024 blocks, 1 wave per batch item
    afm_kernel<<<grid, BLOCK, 0, stream>>>(
        dense, sparse, tables, attW, attB, attH, attP,
        wDense, wSparse, linB, out);
}

// Round 10
// 14.094 us; speedup vs baseline: 14.5808x; 14.5808x over previous
//
#include <hip/hip_runtime.h>
#include <hip/hip_bf16.h>

typedef float v2f    __attribute__((ext_vector_type(2)));
typedef float v4f    __attribute__((ext_vector_type(4)));
typedef float f32x16 __attribute__((ext_vector_type(16)));
typedef __bf16 bf16x8 __attribute__((ext_vector_type(8)));

#define BATCH 4096
#define NF 26
#define NV 100000
#define ND_ 16      // embedding dim D (= MFMA K)
#define NA 16       // attention dim A
#define NDENSE 13
#define NPAIR 325   // NF*(NF-1)/2
#define ROWP 20     // padded LDS row stride in floats (80B)
#define WPB 4       // items per block (2 waves each)
#define BLOCK 512   // 8 waves
#define NTILE 11    // ceil(325/32) MFMA tiles per item

__global__ __launch_bounds__(BLOCK, 8) void afm_kernel(
    const float* __restrict__ dense,     // [B, 13]
    const int*   __restrict__ sparse,    // [B, 26]
    const float* __restrict__ tables,    // [26, 100000, 16]
    const float* __restrict__ attW,      // [16, 16] row-major [d][k]
    const float* __restrict__ attB,      // [16]
    const float* __restrict__ attH,      // [16]
    const float* __restrict__ attP,      // [16]
    const float* __restrict__ wDense,    // [13]
    const float* __restrict__ wSparse,   // [416]
    const float* __restrict__ linB,      // [1]
    float* __restrict__ out)             // [B]
{
    __shared__ int sOFF[NPAIR];                       // (i*ROWP) | (j*ROWP)<<16
    __shared__ __align__(16) float sEmb[WPB][NF * ROWP];
    __shared__ float sPart[WPB][2][3];                // {num, den, lin} per sub-wave

    const int tid  = threadIdx.x;
    const int wave = tid >> 6;
    const int lane = tid & 63;
    const int item = wave >> 1;   // 0..3
    const int subw = wave & 1;    // 0: tiles 0-5, 1: tiles 6-10
    const int col  = lane & 31;   // MFMA column (pair slot)
    const int hi   = lane >> 5;   // K-half: supplies k = hi*8 .. hi*8+7
    const int b    = blockIdx.x * WPB + item;

    // ---- sparse indices: direct load + shfl broadcast ----
    int idxreg = 0;
    if (lane < NF) idxreg = sparse[b * NF + lane];

    // ---- gather embeddings: 104 float4 per item over 128 lanes (1 round) ----
    {
        const int c = subw * 64 + lane;
        if (c < (NF * ND_) / 4) {
            const int f  = c >> 2;
            const int d4 = (c & 3) << 2;
            const int row = __shfl(idxreg, f);
            const float4 v = *reinterpret_cast<const float4*>(
                tables + ((size_t)f * NV + (size_t)row) * ND_ + d4);
            *reinterpret_cast<float4*>(&sEmb[item][f * ROWP + d4]) = v;
        }
    }

    // ---- pair offset table (block-shared, one shot: BLOCK >= NPAIR) ----
    if (tid < NPAIR) {
        int i = 0, rem = tid;
        while (rem >= NF - 1 - i) { rem -= NF - 1 - i; ++i; }
        const int j = i + 1 + rem;
        sOFF[tid] = (i * ROWP) | ((j * ROWP) << 16);
    }

    // ---- A-fragment: rows 0..15 = W^T, row 16 = att_p ----
    bf16x8 afrag;
    #pragma unroll
    for (int t = 0; t < 8; ++t) {
        float a = 0.f;
        if (col < NA)       a = attW[(hi * 8 + t) * NA + col];
        else if (col == NA) a = attP[hi * 8 + t];
        afrag[t] = (__bf16)a;
    }
    // per-lane post weights (packed): acc reg r holds z-row k=(r&3)+8*(r>>2)+4*hi
    v2f h2[4], b2[4];
    #pragma unroll
    for (int r = 0; r < 8; ++r) {
        const int k = (r & 3) + 8 * (r >> 2) + 4 * hi;
        h2[r >> 1][r & 1] = attH[k];
        b2[r >> 1][r & 1] = attB[k];   // bias added post-MFMA (keeps VGPR <= 64)
    }

    __syncthreads();   // sOFF + sEmb visible

    const float* __restrict__ semb = sEmb[item];

    // ---- linear term: split across the item's 2 waves ----
    float lin = 0.f;
    #pragma unroll
    for (int rnd = 0; rnd < 4; ++rnd) {
        const int e = subw * 64 + lane + rnd * 128;
        if (e < NF * ND_)
            lin += semb[(e >> 4) * ROWP + (e & 15)] * wSparse[e];
    }
    if (subw == 0 && lane < NDENSE)
        lin += dense[b * NDENSE + lane] * wDense[lane];

    // ---- tile body (NT becomes compile-time after inlining) ----
    float num = 0.f, den = 0.f;
    auto tiles = [&](const int t0, const int NT) {
        #pragma unroll
        for (int tt = 0; tt < NT; ++tt) {
            const int t     = t0 + tt;
            const int p     = t * 32 + col;
            const bool valid = (p < NPAIR) && (hi == 0);
            const int pc    = (p < NPAIR) ? p : (NPAIR - 1);
            const int offs  = sOFF[pc];
            const float* ri = semb + (offs & 0xffff) + hi * 8;
            const float* rj = semb + (offs >> 16)    + hi * 8;

            const v4f x0 = *reinterpret_cast<const v4f*>(ri);
            const v4f x1 = *reinterpret_cast<const v4f*>(ri + 4);
            const v4f y0 = *reinterpret_cast<const v4f*>(rj);
            const v4f y1 = *reinterpret_cast<const v4f*>(rj + 4);
            const v4f e0 = x0 * y0;      // v_pk_mul_f32
            const v4f e1 = x1 * y1;

            bf16x8 bfrag;                 // B[k=hi*8+t][col] = EWP[pair][d]
            bfrag[0] = (__bf16)e0[0]; bfrag[1] = (__bf16)e0[1];
            bfrag[2] = (__bf16)e0[2]; bfrag[3] = (__bf16)e0[3];
            bfrag[4] = (__bf16)e1[0]; bfrag[5] = (__bf16)e1[1];
            bfrag[6] = (__bf16)e1[2]; bfrag[7] = (__bf16)e1[3];

            f32x16 acc = {0.f,0.f,0.f,0.f,0.f,0.f,0.f,0.f,
                          0.f,0.f,0.f,0.f,0.f,0.f,0.f,0.f};
            acc = __builtin_amdgcn_mfma_f32_32x32x16_bf16(afrag, bfrag, acc, 0, 0, 0);

            // relu(z)·h over this lane's 8 z-rows, bias post-added (packed v2f)
            v2f sp2 = {0.f, 0.f};
            #pragma unroll
            for (int r = 0; r < 4; ++r) {
                v2f z; z.x = acc[2 * r]; z.y = acc[2 * r + 1];
                z = z + b2[r];
                v2f zr; zr.x = fmaxf(z.x, 0.f); zr.y = fmaxf(z.y, 0.f);
                sp2 = zr * h2[r] + sp2;
            }
            const float sp = sp2.x + sp2.y;
            const float sfull = sp + __shfl_xor(sp, 32);

            // scores O(1e-5): exp without max-subtraction is exact-safe
            const float ev = valid ? __expf(sfull) : 0.f;
            num = fmaf(ev, acc[8], num);   // dp = row 16 (hi=0 lanes), no bias
            den += ev;
        }
    };
    if (subw == 0) tiles(0, 6); else tiles(6, 5);

    // ---- per-wave reduce, stash partials ----
    #pragma unroll
    for (int o = 32; o; o >>= 1) {
        num += __shfl_xor(num, o);
        den += __shfl_xor(den, o);
        lin += __shfl_xor(lin, o);
    }
    if (lane == 0) {
        sPart[item][subw][0] = num;
        sPart[item][subw][1] = den;
        sPart[item][subw][2] = lin;
    }
    __syncthreads();

    // ---- combine the item's 2 waves, finalize ----
    if (subw == 0 && lane == 0) {
        const float n = sPart[item][0][0] + sPart[item][1][0];
        const float d = sPart[item][0][1] + sPart[item][1][1];
        const float l = sPart[item][0][2] + sPart[item][1][2];
        const float x = n / d + l + linB[0];
        out[b] = 1.f / (1.f + __expf(-x));
    }
}

extern "C" void kernel_launch(void* const* d_in, const int* in_sizes, int n_in,
                              void* d_out, int out_size, void* d_ws, size_t ws_size,
                              hipStream_t stream) {
    const float* dense   = (const float*)d_in[0];
    const int*   sparse  = (const int*)d_in[1];
    const float* tables  = (const float*)d_in[2];
    const float* attW    = (const float*)d_in[3];
    const float* attB    = (const float*)d_in[4];
    const float* attH    = (const float*)d_in[5];
    const float* attP    = (const float*)d_in[6];
    const float* wDense  = (const float*)d_in[7];
    const float* wSparse = (const float*)d_in[8];
    const float* linB    = (const float*)d_in[9];
    float* out = (float*)d_out;

    const int grid = BATCH / WPB;  // 1024 blocks x 512 threads = 32 waves/CU
    afm_kernel<<<grid, BLOCK, 0, stream>>>(
        dense, sparse, tables, attW, attB, attH, attP,
        wDense, wSparse, linB, out);
}

// Round 11
// 13.432 us; speedup vs baseline: 15.2992x; 1.0493x over previous
//
#include <hip/hip_runtime.h>
#include <hip/hip_bf16.h>

typedef float  v2f    __attribute__((ext_vector_type(2)));
typedef float  f32x16 __attribute__((ext_vector_type(16)));
typedef _Float16 half8 __attribute__((ext_vector_type(8)));
typedef _Float16 half4v __attribute__((ext_vector_type(4)));

#define BATCH 4096
#define NF 26
#define NV 100000
#define ND_ 16      // embedding dim D (= MFMA K)
#define NA 16       // attention dim A
#define NDENSE 13
#define NPAIR 325   // NF*(NF-1)/2
#define ROWH 24     // fp16 elems per LDS row slot (16 valid + 8 pad; 48B)
#define WPB 4       // items per block (2 waves each)
#define BLOCK 512   // 8 waves
#define SCALE 256.0f        // embeddings scaled by 256 -> products x65536
#define INV_SCALE2 (1.0f / 65536.0f)

__global__ __launch_bounds__(BLOCK, 8) void afm_kernel(
    const float* __restrict__ dense,     // [B, 13]
    const int*   __restrict__ sparse,    // [B, 26]
    const float* __restrict__ tables,    // [26, 100000, 16]
    const float* __restrict__ attW,      // [16, 16] row-major [d][k]
    const float* __restrict__ attB,      // [16]
    const float* __restrict__ attH,      // [16]
    const float* __restrict__ attP,      // [16]
    const float* __restrict__ wDense,    // [13]
    const float* __restrict__ wSparse,   // [416]
    const float* __restrict__ linB,      // [1]
    float* __restrict__ out)             // [B]
{
    __shared__ int sOFF[NPAIR];                       // (i*ROWH) | (j*ROWH)<<16
    __shared__ __align__(16) _Float16 sEmbH[WPB][NF * ROWH];
    __shared__ float sPart[WPB][2][3];                // {num, den, lin} per sub-wave

    const int tid  = threadIdx.x;
    const int wave = tid >> 6;
    const int lane = tid & 63;
    const int item = wave >> 1;   // 0..3
    const int subw = wave & 1;    // 0: tiles 0-5, 1: tiles 6-10
    const int col  = lane & 31;   // MFMA column (pair slot)
    const int hi   = lane >> 5;   // K-half: supplies k = hi*8 .. hi*8+7
    const int b    = blockIdx.x * WPB + item;

    // ---- sparse indices: direct load + shfl broadcast ----
    int idxreg = 0;
    if (lane < NF) idxreg = sparse[b * NF + lane];

    // ---- gather: fp32 load -> linear partial (exact) -> x256 fp16 LDS store ----
    float lin = 0.f;
    {
        const int c = subw * 64 + lane;     // 104 float4 per item over 128 lanes
        if (c < (NF * ND_) / 4) {
            const int f  = c >> 2;
            const int d4 = (c & 3) << 2;
            const int row = __shfl(idxreg, f);
            const float4 v = *reinterpret_cast<const float4*>(
                tables + ((size_t)f * NV + (size_t)row) * ND_ + d4);
            const float4 w = *reinterpret_cast<const float4*>(wSparse + f * ND_ + d4);
            lin += v.x * w.x + v.y * w.y + v.z * w.z + v.w * w.w;
            half4v hv;
            hv[0] = (_Float16)(v.x * SCALE);
            hv[1] = (_Float16)(v.y * SCALE);
            hv[2] = (_Float16)(v.z * SCALE);
            hv[3] = (_Float16)(v.w * SCALE);
            *reinterpret_cast<half4v*>(&sEmbH[item][f * ROWH + d4]) = hv;  // 8B store
        }
    }
    if (subw == 0 && lane < NDENSE)
        lin += dense[b * NDENSE + lane] * wDense[lane];

    // ---- pair offset table (block-shared, one shot: BLOCK >= NPAIR) ----
    if (tid < NPAIR) {
        int i = 0, rem = tid;
        while (rem >= NF - 1 - i) { rem -= NF - 1 - i; ++i; }
        const int j = i + 1 + rem;
        sOFF[tid] = (i * ROWH) | ((j * ROWH) << 16);
    }

    // ---- A-fragment (fp16, UNscaled): rows 0..15 = W^T, row 16 = att_p ----
    half8 afrag;
    #pragma unroll
    for (int t = 0; t < 8; ++t) {
        float a = 0.f;
        if (col < NA)       a = attW[(hi * 8 + t) * NA + col];
        else if (col == NA) a = attP[hi * 8 + t];
        afrag[t] = (_Float16)a;
    }
    // per-lane post weights (packed): acc reg r holds z-row k=(r&3)+8*(r>>2)+4*hi
    // z' = 65536*z  ->  h2 = h/65536 ; bias enters as 65536*b
    v2f h2[4], b2[4];
    #pragma unroll
    for (int r = 0; r < 8; ++r) {
        const int k = (r & 3) + 8 * (r >> 2) + 4 * hi;
        h2[r >> 1][r & 1] = attH[k] * INV_SCALE2;
        b2[r >> 1][r & 1] = attB[k] * 65536.0f;
    }

    __syncthreads();   // sOFF + sEmbH visible

    const _Float16* __restrict__ embH = sEmbH[item];

    // ---- tile body (NT compile-time after inlining) ----
    float num = 0.f, den = 0.f;
    auto tiles = [&](const int t0, const int NT) {
        #pragma unroll
        for (int tt = 0; tt < NT; ++tt) {
            const int t     = t0 + tt;
            const int p     = t * 32 + col;
            const bool valid = (p < NPAIR) && (hi == 0);
            const int pc    = (p < NPAIR) ? p : (NPAIR - 1);
            const int offs  = sOFF[pc];

            // one 16B read per row-half (8 fp16)
            const half8 ai = *reinterpret_cast<const half8*>(embH + (offs & 0xffff) + hi * 8);
            const half8 aj = *reinterpret_cast<const half8*>(embH + (offs >> 16)    + hi * 8);
            const half8 bfrag = ai * aj;   // 4x v_pk_mul_f16 — B-fragment ready

            f32x16 acc = {0.f,0.f,0.f,0.f,0.f,0.f,0.f,0.f,
                          0.f,0.f,0.f,0.f,0.f,0.f,0.f,0.f};
            acc = __builtin_amdgcn_mfma_f32_32x32x16_f16(afrag, bfrag, acc, 0, 0, 0);

            // relu(z'+b')·h' over this lane's 8 z-rows (packed v2f)
            v2f sp2 = {0.f, 0.f};
            #pragma unroll
            for (int r = 0; r < 4; ++r) {
                v2f z; z.x = acc[2 * r]; z.y = acc[2 * r + 1];
                z = z + b2[r];
                v2f zr; zr.x = fmaxf(z.x, 0.f); zr.y = fmaxf(z.y, 0.f);
                sp2 = zr * h2[r] + sp2;
            }
            const float sp = sp2.x + sp2.y;
            const float sfull = sp + __shfl_xor(sp, 32);

            // scores O(1e-5): exp without max-subtraction is exact-safe
            const float ev = valid ? __expf(sfull) : 0.f;
            num = fmaf(ev, acc[8], num);   // acc[8] = 65536*dp (row 16, hi=0)
            den += ev;
        }
    };
    if (subw == 0) tiles(0, 6); else tiles(6, 5);

    // ---- per-wave reduce, stash partials ----
    #pragma unroll
    for (int o = 32; o; o >>= 1) {
        num += __shfl_xor(num, o);
        den += __shfl_xor(den, o);
        lin += __shfl_xor(lin, o);
    }
    if (lane == 0) {
        sPart[item][subw][0] = num;
        sPart[item][subw][1] = den;
        sPart[item][subw][2] = lin;
    }
    __syncthreads();

    // ---- combine the item's 2 waves, finalize ----
    if (subw == 0 && lane == 0) {
        const float n = sPart[item][0][0] + sPart[item][1][0];
        const float d = sPart[item][0][1] + sPart[item][1][1];
        const float l = sPart[item][0][2] + sPart[item][1][2];
        const float x = (n * INV_SCALE2) / d + l + linB[0];
        out[b] = 1.f / (1.f + __expf(-x));
    }
}

extern "C" void kernel_launch(void* const* d_in, const int* in_sizes, int n_in,
                              void* d_out, int out_size, void* d_ws, size_t ws_size,
                              hipStream_t stream) {
    const float* dense   = (const float*)d_in[0];
    const int*   sparse  = (const int*)d_in[1];
    const float* tables  = (const float*)d_in[2];
    const float* attW    = (const float*)d_in[3];
    const float* attB    = (const float*)d_in[4];
    const float* attH    = (const float*)d_in[5];
    const float* attP    = (const float*)d_in[6];
    const float* wDense  = (const float*)d_in[7];
    const float* wSparse = (const float*)d_in[8];
    const float* linB    = (const float*)d_in[9];
    float* out = (float*)d_out;

    const int grid = BATCH / WPB;  // 1024 blocks x 512 threads = 32 waves/CU
    afm_kernel<<<grid, BLOCK, 0, stream>>>(
        dense, sparse, tables, attW, attB, attH, attP,
        wDense, wSparse, linB, out);
}